// Round 8
// baseline (389.204 us; speedup 1.0000x reference)
//
#include <hip/hip_runtime.h>

// Attend: out = softmax(causal(Q K^T * 0.125 + bias)) @ V
// B=4,H=16,N=1024,D=64. fp32 I/O, bf16 MFMA compute.
// Round 6 kernel, third submit (two infra failures, source audited clean:
// uniform barriers, in-bounds accesses, 26.6KB LDS — nothing that can hang
// a container; prior-round idioms identical and ran fine).
// CONCURRENCY theory: r4's 512-thr blocks left 2 lockstep barrier groups
// per CU (stragglers: 1) -> dependent latency exposed. 256-thr/4-wave
// blocks, grid 1024 -> 4 independent barrier groups/CU; r3 balanced qt map
// (sum(qt+1)=34 per co-resident set). Keeps: 1-tile-ahead reg prefetch,
// cvt_pk staging, raw lgkm-only barriers, single bias buf, setprio.

#define BHn 64
#define Nn 1024
#define Dn 64
#define NEG_BIG (-1e30f)
#define STR 72    // k/v row stride in shorts (144 B: frag reads at bank floor)
#define STRP 64   // p row stride in shorts (128 B)

typedef __attribute__((ext_vector_type(8))) short short8;
typedef __attribute__((ext_vector_type(4))) float floatx4;
typedef __attribute__((ext_vector_type(2))) unsigned uint2v;
typedef __attribute__((ext_vector_type(4))) unsigned uint4v;

// Barrier without the vmcnt(0) drain __syncthreads() emits: own-LDS drain
// only; global prefetches stay in flight across it.
#define BARRIER_LDS()                                            \
    do {                                                         \
        asm volatile("s_waitcnt lgkmcnt(0)" ::: "memory");       \
        __builtin_amdgcn_s_barrier();                            \
    } while (0)

__device__ __forceinline__ unsigned cvt_pk_bf16(float lo, float hi) {
    unsigned r;
    asm("v_cvt_pk_bf16_f32 %0, %1, %2" : "=v"(r) : "v"(lo), "v"(hi));
    return r;   // packed {bf16(lo), bf16(hi)}, RNE
}

// ---- prefetch tile JT's K/V slice into regs (global, coalesced) ----
#define PREFETCH_KV(JT)                                                      \
    do {                                                                     \
        const float* kb = kk + ((long)(bh * Nn + (JT) * 64)) * Dn;           \
        _Pragma("unroll")                                                    \
        for (int it = 0; it < 4; ++it)                                       \
            kpf[it] = *(const floatx4*)(kb + it * 1024 + tid * 4);           \
        const float* vb = v + ((long)(bh * Nn + (JT) * 64 + wave * 16)) * Dn \
                            + lane;                                          \
        _Pragma("unroll")                                                    \
        for (int r = 0; r < 16; ++r) vpf[r] = vb[r * Dn];                    \
    } while (0)

// ---- stage regs -> LDS (cvt + ds_write only; vmcnt wait is for loads
//      issued a full tile earlier) ----
#define STAGE_KV()                                                           \
    do {                                                                     \
        _Pragma("unroll")                                                    \
        for (int it = 0; it < 4; ++it) {                                     \
            const int e = it * 1024 + tid * 4;                               \
            uint2v w;                                                        \
            w.x = cvt_pk_bf16(kpf[it][0], kpf[it][1]);                       \
            w.y = cvt_pk_bf16(kpf[it][2], kpf[it][3]);                       \
            *(uint2v*)&k_s[e >> 6][e & 63] = w;                              \
        }                                                                    \
        uint4v lo, hi;                                                       \
        lo.x = cvt_pk_bf16(vpf[0],  vpf[1]);                                 \
        lo.y = cvt_pk_bf16(vpf[2],  vpf[3]);                                 \
        lo.z = cvt_pk_bf16(vpf[4],  vpf[5]);                                 \
        lo.w = cvt_pk_bf16(vpf[6],  vpf[7]);                                 \
        hi.x = cvt_pk_bf16(vpf[8],  vpf[9]);                                 \
        hi.y = cvt_pk_bf16(vpf[10], vpf[11]);                                \
        hi.z = cvt_pk_bf16(vpf[12], vpf[13]);                                \
        hi.w = cvt_pk_bf16(vpf[14], vpf[15]);                                \
        *(uint4v*)&vt_s[lane][wave * 16]     = lo;                           \
        *(uint4v*)&vt_s[lane][wave * 16 + 8] = hi;                           \
    } while (0)

// ---- bias loads for tile JT ----
#define LOAD_BIAS(JT)                                                        \
    do {                                                                     \
        if ((JT) <= qt) {                                                    \
            const float* bp = bias + bias_base                               \
                              + (long)(irow0 + lg * 4) * Nn + (JT) * 64 + ln;\
            _Pragma("unroll")                                                \
            for (int r = 0; r < 4; ++r)                                      \
                _Pragma("unroll")                                            \
                for (int c = 0; c < 4; ++c)                                  \
                    bv[c][r] = bp[r * Nn + c * 16];                          \
        }                                                                    \
    } while (0)

__global__ __launch_bounds__(256, 4) void attend_mfma(
    const float* __restrict__ q, const float* __restrict__ kk,
    const float* __restrict__ v, const float* __restrict__ bias,
    float* __restrict__ out)
{
    // ---- balanced (head, qtile): co-resident {c,c+256,c+512,c+768} has
    //      kq_=0..3 -> sum(qt+1)=34 exactly (r3 map) ----
    const int b  = blockIdx.x;
    const int bh = b & 63;
    const int t  = b >> 6;                   // 0..15
    const int kq_ = t >> 2, t0 = t & 3;
    const int qt = kq_ + 4 * ((t0 + kq_ + bh) & 3);   // bijective per head
    const int i0 = qt * 64;

    const int tid  = threadIdx.x;
    const int lane = tid & 63;
    const int wave = tid >> 6;               // 0..3
    const int ln = lane & 15;                // MFMA n / m index
    const int lg = lane >> 4;                // MFMA k-group / row-group
    const int irow0 = i0 + wave * 16;
    const long bias_base = ((long)bh) << 20; // bh * N * N

    __shared__ short k_s[64][STR];           // K tile, row-major [j][d]
    __shared__ short vt_s[64][STR];          // V tile, transposed [d][j]
    __shared__ short p_s[4][16][STRP];       // per-wave P tile [m][j]

    // ---- preload Q A-frags, fp32 -> bf16 ----
    short8 qa[2];
    {
        const float* qp = q + ((long)(bh * Nn + irow0 + ln)) * Dn + lg * 8;
#pragma unroll
        for (int kp = 0; kp < 2; ++kp) {
            floatx4 f0 = *(const floatx4*)(qp + kp * 32);
            floatx4 f1 = *(const floatx4*)(qp + kp * 32 + 4);
            union { short8 s; unsigned u[4]; } qq;
            qq.u[0] = cvt_pk_bf16(f0[0], f0[1]);
            qq.u[1] = cvt_pk_bf16(f0[2], f0[3]);
            qq.u[2] = cvt_pk_bf16(f1[0], f1[1]);
            qq.u[3] = cvt_pk_bf16(f1[2], f1[3]);
            qa[kp] = qq.s;
        }
    }

    short8 ones;
#pragma unroll
    for (int i = 0; i < 8; ++i) ones[i] = (short)0x3F80;   // bf16 1.0

    floatx4 o_acc[4];
#pragma unroll
    for (int dt = 0; dt < 4; ++dt) o_acc[dt] = (floatx4){0.f, 0.f, 0.f, 0.f};
    floatx4 l_acc = {0.f, 0.f, 0.f, 0.f};

    // ---- register prefetch buffers (all statically indexed) ----
    floatx4 kpf[4];      // 16 floats: K tile slice
    float   vpf[16];     // 16 floats: V tile slice (col=lane, 16 rows)
    float   bv[4][4];    // bias for the CURRENT tile

    // ---- prologue ----
    PREFETCH_KV(0);
    LOAD_BIAS(0);

    for (int jt = 0; jt <= qt; ++jt) {
        BARRIER_LDS();                       // prior-tile LDS readers done
        STAGE_KV();                          // tile jt: cvt + ds_write only
        BARRIER_LDS();                       // tile jt visible

        if (jt < qt) PREFETCH_KV(jt + 1);    // in flight across whole compute

        // ---- S = Q K^T, exp folded per-nt_ (one 4-reg acc live) ----
        const bool diag = (jt == qt);
#pragma unroll
        for (int nt_ = 0; nt_ < 4; ++nt_) {
            short8 b0 = *(const short8*)&k_s[nt_ * 16 + ln][lg * 8];
            short8 b1 = *(const short8*)&k_s[nt_ * 16 + ln][32 + lg * 8];
            floatx4 acc = {0.f, 0.f, 0.f, 0.f};
            __builtin_amdgcn_s_setprio(1);
            acc = __builtin_amdgcn_mfma_f32_16x16x32_bf16(qa[0], b0, acc, 0, 0, 0);
            acc = __builtin_amdgcn_mfma_f32_16x16x32_bf16(qa[1], b1, acc, 0, 0, 0);
            __builtin_amdgcn_s_setprio(0);
#pragma unroll
            for (int r = 0; r < 4; ++r) {
                float sv = acc[r] * 0.125f + bv[nt_][r];
                if (diag) {
                    const int i_ = irow0 + lg * 4 + r;
                    const int j_ = jt * 64 + nt_ * 16 + ln;
                    sv = (j_ > i_) ? NEG_BIG : sv;
                }
                const float p  = __expf(sv);
                const float po = __shfl_xor(p, 1);
                if (!(lane & 1))             // even lane packs (ln, ln+1) -> b32
                    *(unsigned*)&p_s[wave][lg * 4 + r][nt_ * 16 + ln] =
                        cvt_pk_bf16(p, po);
            }
        }

        LOAD_BIAS(jt + 1);                   // bv dead; next tile's bias

        // ---- P A-frags (wave-local LDS round trip) ----
        const short8 pa0 = *(const short8*)&p_s[wave][ln][lg * 8];
        const short8 pa1 = *(const short8*)&p_s[wave][ln][32 + lg * 8];

        __builtin_amdgcn_s_setprio(1);
        l_acc = __builtin_amdgcn_mfma_f32_16x16x32_bf16(pa0, ones, l_acc, 0, 0, 0);
        l_acc = __builtin_amdgcn_mfma_f32_16x16x32_bf16(pa1, ones, l_acc, 0, 0, 0);
#pragma unroll
        for (int dt = 0; dt < 4; ++dt) {
            short8 vb0 = *(const short8*)&vt_s[dt * 16 + ln][lg * 8];
            short8 vb1 = *(const short8*)&vt_s[dt * 16 + ln][32 + lg * 8];
            o_acc[dt] = __builtin_amdgcn_mfma_f32_16x16x32_bf16(pa0, vb0, o_acc[dt], 0, 0, 0);
            o_acc[dt] = __builtin_amdgcn_mfma_f32_16x16x32_bf16(pa1, vb1, o_acc[dt], 0, 0, 0);
        }
        __builtin_amdgcn_s_setprio(0);
    }

    // ---- epilogue: out = O / l, fp32 stores ----
#pragma unroll
    for (int r = 0; r < 4; ++r) {
        const float linv = 1.0f / l_acc[r];
        const long orow = ((long)(bh * Nn + irow0 + lg * 4 + r)) * Dn;
#pragma unroll
        for (int dt = 0; dt < 4; ++dt)
            out[orow + dt * 16 + ln] = o_acc[dt][r] * linv;
    }
}

extern "C" void kernel_launch(void* const* d_in, const int* in_sizes, int n_in,
                              void* d_out, int out_size, void* d_ws, size_t ws_size,
                              hipStream_t stream) {
    const float* q    = (const float*)d_in[0];
    const float* k    = (const float*)d_in[1];
    const float* v    = (const float*)d_in[2];
    const float* bias = (const float*)d_in[3];
    float* out = (float*)d_out;

    dim3 grid(1024);   // 64 heads x 16 q-tiles of 64 rows
    dim3 block(256);   // 4 waves x 16 rows
    attend_mfma<<<grid, block, 0, stream>>>(q, k, v, bias, out);
}